// Round 1
// baseline (254.850 us; speedup 1.0000x reference)
//
#include <hip/hip_runtime.h>

#define NCLS 21
#define HW (512 * 512)
#define QP (HW / 4)                  // 65536 float4-quads per image
#define BATCH 8
#define BLOCK 256
#define QPT 2                        // quads per thread
#define BPI (QP / (BLOCK * QPT))     // 128 blocks per image
#define NB (BATCH * BPI)             // 1024 partial columns

// ws layout (floats): ws[r * NB + col], r in [0,42)
//   r <  21 : union partial for class r
//   r >= 21 : intersect partial for class r-21
//   col = b * BPI + blk   (written non-atomically by exactly one block; no pre-zero needed)

__device__ __forceinline__ float comp(const float4& v, int j) {
    // j is compile-time constant after full unroll -> folds to a register pick
    return j == 0 ? v.x : j == 1 ? v.y : j == 2 ? v.z : v.w;
}

__global__ __launch_bounds__(BLOCK) void iou_partial_kernel(
        const float* __restrict__ in,   // [B, C, H, W] fp32 logits
        const int*   __restrict__ tgt,  // [B, H, W] int32 labels
        float* __restrict__ ws) {
    const int b   = blockIdx.y;
    const int blk = blockIdx.x;
    const float4* __restrict__ in4 = (const float4*)(in + (size_t)b * NCLS * HW);
    const int4*   __restrict__ tg4 = (const int4*)(tgt + (size_t)b * HW);

    __shared__ float s_u[NCLS];
    __shared__ float s_i[NCLS];
    if (threadIdx.x < NCLS) { s_u[threadIdx.x] = 0.0f; s_i[threadIdx.x] = 0.0f; }
    __syncthreads();

    #pragma unroll
    for (int it = 0; it < QPT; ++it) {
        const int q = (blk * QPT + it) * BLOCK + threadIdx.x;  // coalesced per iter
        const int4 t4 = tg4[q];
        float4 x[NCLS];
        #pragma unroll
        for (int c = 0; c < NCLS; ++c)
            x[c] = in4[(size_t)c * QP + q];                    // 16 B/lane, coalesced

        const int tj4[4] = {t4.x, t4.y, t4.z, t4.w};
        #pragma unroll
        for (int j = 0; j < 4; ++j) {
            const int tj = tj4[j];
            // pass 1: max + argmax (strict >, first index on tie)
            float m  = comp(x[0], j);
            int   aj = 0;
            #pragma unroll
            for (int c = 1; c < NCLS; ++c) {
                const float v = comp(x[c], j);
                const bool g = v > m;
                aj = g ? c : aj;
                m  = g ? v : m;
            }
            // pass 2: sum of exp + select e_target in the same sweep
            float s  = 0.0f;
            float et = 0.0f;
            #pragma unroll
            for (int c = 0; c < NCLS; ++c) {
                const float v = comp(x[c], j);
                const float e = __expf(v - m);
                s += e;
                et = (c == tj) ? e : et;
            }
            const float p_pred = 1.0f / s;        // exp(m-m)/s
            const float p_t    = et * p_pred;
            const bool  eq = (tj == aj);
            // union 2->1 clamp: if eq, one union add + one intersect add;
            // else two union adds. Exactly 2 LDS atomics/pixel, branchless.
            atomicAdd(&s_u[aj], p_pred);
            atomicAdd(eq ? &s_i[aj] : &s_u[tj], eq ? p_pred : p_t);
        }
    }

    __syncthreads();
    // Non-atomic per-block partial write: 42 floats, one column per block.
    if (threadIdx.x < 2 * NCLS) {
        const float v = (threadIdx.x < NCLS) ? s_u[threadIdx.x]
                                             : s_i[threadIdx.x - NCLS];
        ws[(size_t)threadIdx.x * NB + b * BPI + blk] = v;
    }
}

__global__ __launch_bounds__(256) void finalize_kernel(
        const float* __restrict__ ws, float* __restrict__ out) {
    __shared__ float red[256];
    const int i = threadIdx.x;
    float val = 0.0f;
    if (i < BATCH * NCLS) {
        const int b = i / NCLS;
        const int c = i % NCLS;
        // Each (b,c) sums its 128 contiguous block-partials (float4-vectorized).
        const float4* __restrict__ u4 =
            (const float4*)(ws + (size_t)c * NB + b * BPI);
        const float4* __restrict__ i4 =
            (const float4*)(ws + (size_t)(NCLS + c) * NB + b * BPI);
        float u = 0.0f, t = 0.0f;
        #pragma unroll 8
        for (int k = 0; k < BPI / 4; ++k) {
            const float4 a = u4[k];
            u += a.x + a.y + a.z + a.w;
            const float4 d = i4[k];
            t += d.x + d.y + d.z + d.w;
        }
        const float ratio = t / fmaxf(u, 1.0f);
        const float dd = ratio - 1.0f;
        val = dd * dd;
    }
    red[i] = val;
    __syncthreads();
    for (int off = 128; off > 0; off >>= 1) {
        if (i < off) red[i] += red[i + off];
        __syncthreads();
    }
    if (i == 0) out[0] = red[0] / (float)BATCH;
}

extern "C" void kernel_launch(void* const* d_in, const int* in_sizes, int n_in,
                              void* d_out, int out_size, void* d_ws, size_t ws_size,
                              hipStream_t stream) {
    const float* in  = (const float*)d_in[0];
    const int*   tgt = (const int*)d_in[1];
    float* ws  = (float*)d_ws;
    float* out = (float*)d_out;

    dim3 grid(BPI, BATCH);
    iou_partial_kernel<<<grid, BLOCK, 0, stream>>>(in, tgt, ws);
    finalize_kernel<<<1, 256, 0, stream>>>(ws, out);
}